// Round 1
// baseline (326.094 us; speedup 1.0000x reference)
//
#include <hip/hip_runtime.h>
#include <hip/hip_bf16.h>

// ---------------------------------------------------------------------------
// LearnedMeans: 2-NN distances (queries=learned_means vs {true_means, X_train})
// + statistics (counts, means, percentiles).
//
// Sizes (fixed by reference):
//   learned_means: [1024, 512] f32
//   true_means:    [4096, 512] f32
//   X_train:       [16384,512] f32
//   out:           [16] f32
// ---------------------------------------------------------------------------

#define DIM 512
#define M_Q 1024
#define P_TM 4096
#define P_XT 16384
#define BM 64
#define BN 64
#define BK 32
#define LDSROW 40           // bf16 elems per LDS row (32 + 8 pad) -> 80 B, 16B aligned
#define NCHUNK_TM (P_TM / BN)            // 64
#define NCHUNK_XT (P_XT / BN)            // 256
#define NCHUNK_TOT (NCHUNK_TM + NCHUNK_XT) // 320
#define BIGF 3.402823466e38f

typedef __bf16 bf16x8 __attribute__((ext_vector_type(8)));
typedef float f32x4 __attribute__((ext_vector_type(4)));
typedef unsigned short u16x8 __attribute__((ext_vector_type(8)));

__device__ __forceinline__ unsigned short f2bf(float f) {
    // round-to-nearest-even f32 -> bf16 bits (no NaN handling needed here)
    unsigned int u = __float_as_uint(f);
    unsigned int r = (u + 0x7fffu + ((u >> 16) & 1u)) >> 16;
    return (unsigned short)r;
}

__device__ __forceinline__ void merge1(float v, float& d1, float& d2) {
    if (v < d1) { d2 = d1; d1 = v; }
    else if (v < d2) { d2 = v; }
}

// ---------------------------------------------------------------------------
// Row squared-norms: one wave per row (512 f32 = 8 per lane).
// ---------------------------------------------------------------------------
__global__ __launch_bounds__(256) void norms_kernel(
    const float* __restrict__ src, float* __restrict__ dst, int nrows)
{
    int wid = threadIdx.x >> 6;
    int lane = threadIdx.x & 63;
    int row = blockIdx.x * 4 + wid;
    if (row >= nrows) return;
    const float* p = src + (size_t)row * DIM + lane * 8;
    float4 v0 = *(const float4*)p;
    float4 v1 = *(const float4*)(p + 4);
    float s = v0.x*v0.x + v0.y*v0.y + v0.z*v0.z + v0.w*v0.w
            + v1.x*v1.x + v1.y*v1.y + v1.z*v1.z + v1.w*v1.w;
    #pragma unroll
    for (int off = 32; off > 0; off >>= 1) s += __shfl_xor(s, off);
    if (lane == 0) dst[row] = s;
}

// ---------------------------------------------------------------------------
// Distance + per-chunk top-2.
// Block tile: BM=64 queries x BN=64 dataset rows, K swept in BK=32 steps.
// 4 waves; wave w owns rows [w*16, w*16+16) x all 64 cols (4 MFMA 16x16x32 /step).
// Epilogue: sq = q2 + d2 - 2*dot, in-lane top2 over 4 col-tiles, then
// shfl_xor top2 merge over the 16-lane col group. Writes partial[m][chunk][2].
// ---------------------------------------------------------------------------
__global__ __launch_bounds__(256) void dist_top2_kernel(
    const float* __restrict__ Q,     // [M_Q][DIM]
    const float* __restrict__ Dset,  // [P][DIM]
    const float* __restrict__ qn,    // [M_Q]
    const float* __restrict__ dn,    // [P]
    float* __restrict__ partial,     // [M_Q][NCHUNK_TOT][2]
    int chunkGlobalOffset)
{
    __shared__ __align__(16) unsigned short As[BM][LDSROW];
    __shared__ __align__(16) unsigned short Bs[BN][LDSROW];

    const int tid  = threadIdx.x;
    const int lane = tid & 63;
    const int wid  = tid >> 6;                 // 0..3
    const int mBase = blockIdx.y * BM;
    const int nBase = blockIdx.x * BN;

    // staging: thread t loads 8 consecutive f32 of row (t>>2), k-offset (t&3)*8
    const int srow = tid >> 2;                 // 0..63
    const int skc  = (tid & 3) * 8;            // 0,8,16,24

    const float* qrow = Q    + (size_t)(mBase + srow) * DIM + skc;
    const float* drow = Dset + (size_t)(nBase + srow) * DIM + skc;

    f32x4 acc[4];
    #pragma unroll
    for (int nt = 0; nt < 4; ++nt)
        #pragma unroll
        for (int i = 0; i < 4; ++i) acc[nt][i] = 0.0f;

    const int frow = lane & 15;                // fragment row/col within 16-tile
    const int fk   = (lane >> 4) * 8;          // fragment k offset

    for (int ks = 0; ks < DIM; ks += BK) {
        float4 a0 = *(const float4*)(qrow + ks);
        float4 a1 = *(const float4*)(qrow + ks + 4);
        float4 b0 = *(const float4*)(drow + ks);
        float4 b1 = *(const float4*)(drow + ks + 4);

        u16x8 va, vb;
        va[0]=f2bf(a0.x); va[1]=f2bf(a0.y); va[2]=f2bf(a0.z); va[3]=f2bf(a0.w);
        va[4]=f2bf(a1.x); va[5]=f2bf(a1.y); va[6]=f2bf(a1.z); va[7]=f2bf(a1.w);
        vb[0]=f2bf(b0.x); vb[1]=f2bf(b0.y); vb[2]=f2bf(b0.z); vb[3]=f2bf(b0.w);
        vb[4]=f2bf(b1.x); vb[5]=f2bf(b1.y); vb[6]=f2bf(b1.z); vb[7]=f2bf(b1.w);

        *(u16x8*)(&As[srow][skc]) = va;
        *(u16x8*)(&Bs[srow][skc]) = vb;

        __syncthreads();

        bf16x8 af = *(const bf16x8*)(&As[wid * 16 + frow][fk]);
        #pragma unroll
        for (int nt = 0; nt < 4; ++nt) {
            bf16x8 bf = *(const bf16x8*)(&Bs[nt * 16 + frow][fk]);
            acc[nt] = __builtin_amdgcn_mfma_f32_16x16x32_bf16(af, bf, acc[nt], 0, 0, 0);
        }

        __syncthreads();
    }

    // epilogue: C/D layout col=lane&15, row=(lane>>4)*4+r
    const int rbase = mBase + wid * 16 + ((lane >> 4) << 2);
    float q2[4];
    #pragma unroll
    for (int r = 0; r < 4; ++r) q2[r] = qn[rbase + r];

    float d1[4], d2[4];
    #pragma unroll
    for (int r = 0; r < 4; ++r) { d1[r] = BIGF; d2[r] = BIGF; }

    #pragma unroll
    for (int nt = 0; nt < 4; ++nt) {
        float dd = dn[nBase + nt * 16 + (lane & 15)];
        #pragma unroll
        for (int r = 0; r < 4; ++r) {
            float sq = q2[r] + dd - 2.0f * acc[nt][r];
            sq = fmaxf(sq, 0.0f);
            merge1(sq, d1[r], d2[r]);
        }
    }

    // top-2 merge across the 16-lane column group
    #pragma unroll
    for (int off = 1; off < 16; off <<= 1) {
        #pragma unroll
        for (int r = 0; r < 4; ++r) {
            float o1 = __shfl_xor(d1[r], off);
            float o2 = __shfl_xor(d2[r], off);
            float nd1 = fminf(d1[r], o1);
            float nd2 = fminf(fmaxf(d1[r], o1), fminf(d2[r], o2));
            d1[r] = nd1; d2[r] = nd2;
        }
    }

    if ((lane & 15) == 0) {
        int chunkG = chunkGlobalOffset + blockIdx.x;
        #pragma unroll
        for (int r = 0; r < 4; ++r) {
            size_t base = ((size_t)(rbase + r) * NCHUNK_TOT + chunkG) * 2;
            partial[base]     = d1[r];
            partial[base + 1] = d2[r];
        }
    }
}

// ---------------------------------------------------------------------------
// Merge per-chunk top-2 partials -> final top-2 distances per query (sqrt'd).
// fin layout: dm1[0..1024), dm2[1024..2048), ds1[2048..3072), ds2[3072..4096)
// ---------------------------------------------------------------------------
__global__ __launch_bounds__(256) void reduce_top2_kernel(
    const float* __restrict__ partial, float* __restrict__ fin)
{
    int m = blockIdx.x * blockDim.x + threadIdx.x;
    if (m >= M_Q) return;
    const float* p = partial + (size_t)m * NCHUNK_TOT * 2;

    float a1 = BIGF, a2 = BIGF;
    for (int c = 0; c < NCHUNK_TM; ++c) {
        merge1(p[2*c], a1, a2);
        merge1(p[2*c + 1], a1, a2);
    }
    float b1 = BIGF, b2 = BIGF;
    for (int c = NCHUNK_TM; c < NCHUNK_TOT; ++c) {
        merge1(p[2*c], b1, b2);
        merge1(p[2*c + 1], b1, b2);
    }
    fin[m]            = sqrtf(a1);
    fin[M_Q + m]      = sqrtf(a2);
    fin[2*M_Q + m]    = sqrtf(b1);
    fin[3*M_Q + m]    = sqrtf(b2);
}

// ---------------------------------------------------------------------------
// Final stats: counts, means, percentiles (numpy-linear) via bitonic sort.
// Single block, 1024 threads.
// ---------------------------------------------------------------------------
__device__ __forceinline__ void sort_and_pct(float* s, int t, float* dst) {
    __syncthreads();
    for (int k = 2; k <= 1024; k <<= 1) {
        for (int j = k >> 1; j > 0; j >>= 1) {
            __syncthreads();
            int ixj = t ^ j;
            if (ixj > t) {
                float a = s[t], b = s[ixj];
                bool up = ((t & k) == 0);
                if ((a > b) == up) { s[t] = b; s[ixj] = a; }
            }
        }
    }
    __syncthreads();
    if (t < 5) {
        const float P[5] = {10.f, 25.f, 50.f, 75.f, 90.f};
        float q = P[t] * 1023.0f / 100.0f;
        int lo = (int)q;
        float fr = q - (float)lo;
        dst[t] = s[lo] + fr * (s[lo + 1] - s[lo]);
    }
    __syncthreads();
}

__global__ __launch_bounds__(1024) void stats_kernel(
    const float* __restrict__ fin, float* __restrict__ out)
{
    __shared__ float s[1024];
    __shared__ float red[16][6];
    const int t = threadIdx.x;

    float m1 = fin[t];
    float m2 = fin[1024 + t];
    float s1 = fin[2048 + t];
    float s2 = fin[3072 + t];

    const float T = 1.0f / 3.0f;
    float v[6];
    v[0] = (m1 < T * s1 && m1 < T * m2) ? 1.0f : 0.0f;
    v[1] = (s1 < T * m1 && s1 < T * s2) ? 1.0f : 0.0f;
    v[2] = m1; v[3] = s1; v[4] = m2; v[5] = s2;

    #pragma unroll
    for (int off = 32; off > 0; off >>= 1)
        #pragma unroll
        for (int i = 0; i < 6; ++i) v[i] += __shfl_xor(v[i], off);

    int lane = t & 63, wid = t >> 6;
    if (lane == 0) {
        #pragma unroll
        for (int i = 0; i < 6; ++i) red[wid][i] = v[i];
    }
    __syncthreads();
    if (t == 0) {
        float a[6] = {0, 0, 0, 0, 0, 0};
        for (int w = 0; w < 16; ++w)
            for (int i = 0; i < 6; ++i) a[i] += red[w][i];
        out[0] = a[0];
        out[1] = a[1];
        out[2] = a[2] / 1024.0f;
        out[3] = a[3] / 1024.0f;
        out[4] = a[4] / 1024.0f;
        out[5] = a[5] / 1024.0f;
    }

    s[t] = m1;
    sort_and_pct(s, t, out + 6);
    s[t] = s1;
    sort_and_pct(s, t, out + 11);
}

// ---------------------------------------------------------------------------
extern "C" void kernel_launch(void* const* d_in, const int* in_sizes, int n_in,
                              void* d_out, int out_size, void* d_ws, size_t ws_size,
                              hipStream_t stream) {
    const float* Q  = (const float*)d_in[0];   // learned_means [1024,512]
    const float* TM = (const float*)d_in[1];   // true_means   [4096,512]
    const float* XT = (const float*)d_in[2];   // X_train      [16384,512]
    float* out = (float*)d_out;

    float* ws = (float*)d_ws;
    float* qn = ws;                                         // 1024
    float* dn = ws + M_Q;                                   // 20480 (TM then XT)
    float* partial = dn + (P_TM + P_XT);                    // 1024*320*2 = 655360
    float* fin = partial + (size_t)M_Q * NCHUNK_TOT * 2;    // 4096

    norms_kernel<<<dim3(M_Q / 4),  256, 0, stream>>>(Q,  qn, M_Q);
    norms_kernel<<<dim3(P_TM / 4), 256, 0, stream>>>(TM, dn, P_TM);
    norms_kernel<<<dim3(P_XT / 4), 256, 0, stream>>>(XT, dn + P_TM, P_XT);

    dist_top2_kernel<<<dim3(NCHUNK_TM, M_Q / BM), 256, 0, stream>>>(
        Q, TM, qn, dn, partial, 0);
    dist_top2_kernel<<<dim3(NCHUNK_XT, M_Q / BM), 256, 0, stream>>>(
        Q, XT, qn, dn + P_TM, partial, NCHUNK_TM);

    reduce_top2_kernel<<<dim3(M_Q / 256), 256, 0, stream>>>(partial, fin);
    stats_kernel<<<dim3(1), 1024, 0, stream>>>(fin, out);
}

// Round 2
// 139.000 us; speedup vs baseline: 2.3460x; 2.3460x over previous
//
#include <hip/hip_runtime.h>
#include <hip/hip_bf16.h>

// ---------------------------------------------------------------------------
// LearnedMeans: 2-NN distances (queries=learned_means vs {true_means, X_train})
// + statistics (counts, means, percentiles).
//
// Sizes (fixed by reference):
//   learned_means: [1024, 512] f32
//   true_means:    [4096, 512] f32
//   X_train:       [16384,512] f32
//   out:           [16] f32
// ---------------------------------------------------------------------------

#define DIM 512
#define M_Q 1024
#define P_TM 4096
#define P_XT 16384
#define BM 64
#define BN 64
#define BK 32
#define LDSROW 40           // bf16 elems per LDS row (32 + 8 pad) -> 80 B, 16B aligned
#define NCHUNK_TM (P_TM / BN)            // 64
#define NCHUNK_XT (P_XT / BN)            // 256
#define NCHUNK_TOT (NCHUNK_TM + NCHUNK_XT) // 320
#define BIGF 3.402823466e38f

typedef __bf16 bf16x8 __attribute__((ext_vector_type(8)));
typedef float f32x4 __attribute__((ext_vector_type(4)));
typedef unsigned short u16x8 __attribute__((ext_vector_type(8)));

__device__ __forceinline__ unsigned short f2bf(float f) {
    // round-to-nearest-even f32 -> bf16 bits (no NaN handling needed here)
    unsigned int u = __float_as_uint(f);
    unsigned int r = (u + 0x7fffu + ((u >> 16) & 1u)) >> 16;
    return (unsigned short)r;
}

__device__ __forceinline__ void merge1(float v, float& d1, float& d2) {
    if (v < d1) { d2 = d1; d1 = v; }
    else if (v < d2) { d2 = v; }
}

// ---------------------------------------------------------------------------
// Row squared-norms: one wave per row (512 f32 = 8 per lane).
// ---------------------------------------------------------------------------
__global__ __launch_bounds__(256) void norms_kernel(
    const float* __restrict__ src, float* __restrict__ dst, int nrows)
{
    int wid = threadIdx.x >> 6;
    int lane = threadIdx.x & 63;
    int row = blockIdx.x * 4 + wid;
    if (row >= nrows) return;
    const float* p = src + (size_t)row * DIM + lane * 8;
    float4 v0 = *(const float4*)p;
    float4 v1 = *(const float4*)(p + 4);
    float s = v0.x*v0.x + v0.y*v0.y + v0.z*v0.z + v0.w*v0.w
            + v1.x*v1.x + v1.y*v1.y + v1.z*v1.z + v1.w*v1.w;
    #pragma unroll
    for (int off = 32; off > 0; off >>= 1) s += __shfl_xor(s, off);
    if (lane == 0) dst[row] = s;
}

// ---------------------------------------------------------------------------
// Distance + per-chunk top-2.
// Block tile: BM=64 queries x BN=64 dataset rows, K swept in BK=32 steps.
// 4 waves; wave w owns rows [w*16, w*16+16) x all 64 cols (4 MFMA 16x16x32 /step).
// Epilogue: sq = q2 + d2 - 2*dot, in-lane top2 over 4 col-tiles, then
// shfl_xor top2 merge over the 16-lane col group. Writes partial[m][chunk][2].
// ---------------------------------------------------------------------------
__global__ __launch_bounds__(256) void dist_top2_kernel(
    const float* __restrict__ Q,     // [M_Q][DIM]
    const float* __restrict__ Dset,  // [P][DIM]
    const float* __restrict__ qn,    // [M_Q]
    const float* __restrict__ dn,    // [P]
    float* __restrict__ partial,     // [M_Q][NCHUNK_TOT][2]
    int chunkGlobalOffset)
{
    __shared__ __align__(16) unsigned short As[BM][LDSROW];
    __shared__ __align__(16) unsigned short Bs[BN][LDSROW];

    const int tid  = threadIdx.x;
    const int lane = tid & 63;
    const int wid  = tid >> 6;                 // 0..3
    const int mBase = blockIdx.y * BM;
    const int nBase = blockIdx.x * BN;

    // staging: thread t loads 8 consecutive f32 of row (t>>2), k-offset (t&3)*8
    const int srow = tid >> 2;                 // 0..63
    const int skc  = (tid & 3) * 8;            // 0,8,16,24

    const float* qrow = Q    + (size_t)(mBase + srow) * DIM + skc;
    const float* drow = Dset + (size_t)(nBase + srow) * DIM + skc;

    f32x4 acc[4];
    #pragma unroll
    for (int nt = 0; nt < 4; ++nt)
        #pragma unroll
        for (int i = 0; i < 4; ++i) acc[nt][i] = 0.0f;

    const int frow = lane & 15;                // fragment row/col within 16-tile
    const int fk   = (lane >> 4) * 8;          // fragment k offset

    for (int ks = 0; ks < DIM; ks += BK) {
        float4 a0 = *(const float4*)(qrow + ks);
        float4 a1 = *(const float4*)(qrow + ks + 4);
        float4 b0 = *(const float4*)(drow + ks);
        float4 b1 = *(const float4*)(drow + ks + 4);

        u16x8 va, vb;
        va[0]=f2bf(a0.x); va[1]=f2bf(a0.y); va[2]=f2bf(a0.z); va[3]=f2bf(a0.w);
        va[4]=f2bf(a1.x); va[5]=f2bf(a1.y); va[6]=f2bf(a1.z); va[7]=f2bf(a1.w);
        vb[0]=f2bf(b0.x); vb[1]=f2bf(b0.y); vb[2]=f2bf(b0.z); vb[3]=f2bf(b0.w);
        vb[4]=f2bf(b1.x); vb[5]=f2bf(b1.y); vb[6]=f2bf(b1.z); vb[7]=f2bf(b1.w);

        *(u16x8*)(&As[srow][skc]) = va;
        *(u16x8*)(&Bs[srow][skc]) = vb;

        __syncthreads();

        bf16x8 af = *(const bf16x8*)(&As[wid * 16 + frow][fk]);
        #pragma unroll
        for (int nt = 0; nt < 4; ++nt) {
            bf16x8 bf = *(const bf16x8*)(&Bs[nt * 16 + frow][fk]);
            acc[nt] = __builtin_amdgcn_mfma_f32_16x16x32_bf16(af, bf, acc[nt], 0, 0, 0);
        }

        __syncthreads();
    }

    // epilogue: C/D layout col=lane&15, row=(lane>>4)*4+r
    const int rbase = mBase + wid * 16 + ((lane >> 4) << 2);
    float q2[4];
    #pragma unroll
    for (int r = 0; r < 4; ++r) q2[r] = qn[rbase + r];

    float d1[4], d2[4];
    #pragma unroll
    for (int r = 0; r < 4; ++r) { d1[r] = BIGF; d2[r] = BIGF; }

    #pragma unroll
    for (int nt = 0; nt < 4; ++nt) {
        float dd = dn[nBase + nt * 16 + (lane & 15)];
        #pragma unroll
        for (int r = 0; r < 4; ++r) {
            float sq = q2[r] + dd - 2.0f * acc[nt][r];
            sq = fmaxf(sq, 0.0f);
            merge1(sq, d1[r], d2[r]);
        }
    }

    // top-2 merge across the 16-lane column group
    #pragma unroll
    for (int off = 1; off < 16; off <<= 1) {
        #pragma unroll
        for (int r = 0; r < 4; ++r) {
            float o1 = __shfl_xor(d1[r], off);
            float o2 = __shfl_xor(d2[r], off);
            float nd1 = fminf(d1[r], o1);
            float nd2 = fminf(fmaxf(d1[r], o1), fminf(d2[r], o2));
            d1[r] = nd1; d2[r] = nd2;
        }
    }

    if ((lane & 15) == 0) {
        int chunkG = chunkGlobalOffset + blockIdx.x;
        #pragma unroll
        for (int r = 0; r < 4; ++r) {
            size_t base = ((size_t)(rbase + r) * NCHUNK_TOT + chunkG) * 2;
            partial[base]     = d1[r];
            partial[base + 1] = d2[r];
        }
    }
}

// ---------------------------------------------------------------------------
// Merge per-chunk top-2 partials -> final top-2 distances per query (sqrt'd).
// One WAVE per query (R1 rewrite: old version was 4 blocks total, each thread
// serially walking 640 floats -> 195us latency-bound. Now: coalesced vector
// loads + 6-step shfl_xor top-2 merge, 1024 waves).
// fin layout: dm1[0..1024), dm2[1024..2048), ds1[2048..3072), ds2[3072..4096)
// ---------------------------------------------------------------------------
__global__ __launch_bounds__(256) void reduce_top2_kernel(
    const float* __restrict__ partial, float* __restrict__ fin)
{
    const int wid  = threadIdx.x >> 6;
    const int lane = threadIdx.x & 63;
    const int m = blockIdx.x * 4 + wid;
    const float* p = partial + (size_t)m * (NCHUNK_TOT * 2);

    // --- TM chunks 0..63: one chunk (pair) per lane, coalesced float2 ---
    float2 v = *(const float2*)(p + 2 * lane);
    float a1 = fminf(v.x, v.y), a2 = fmaxf(v.x, v.y);
    #pragma unroll
    for (int off = 32; off > 0; off >>= 1) {
        float o1 = __shfl_xor(a1, off);
        float o2 = __shfl_xor(a2, off);
        float n1 = fminf(a1, o1);
        float n2 = fminf(fmaxf(a1, o1), fminf(a2, o2));
        a1 = n1; a2 = n2;
    }

    // --- XT chunks 64..319: 4 chunks (8 floats) per lane, two float4 ---
    const float* px = p + 2 * NCHUNK_TM + lane * 8;
    float4 w0 = *(const float4*)px;
    float4 w1 = *(const float4*)(px + 4);
    float b1 = BIGF, b2 = BIGF;
    merge1(w0.x, b1, b2); merge1(w0.y, b1, b2);
    merge1(w0.z, b1, b2); merge1(w0.w, b1, b2);
    merge1(w1.x, b1, b2); merge1(w1.y, b1, b2);
    merge1(w1.z, b1, b2); merge1(w1.w, b1, b2);
    #pragma unroll
    for (int off = 32; off > 0; off >>= 1) {
        float o1 = __shfl_xor(b1, off);
        float o2 = __shfl_xor(b2, off);
        float n1 = fminf(b1, o1);
        float n2 = fminf(fmaxf(b1, o1), fminf(b2, o2));
        b1 = n1; b2 = n2;
    }

    if (lane == 0) {
        fin[m]           = sqrtf(a1);
        fin[M_Q + m]     = sqrtf(a2);
        fin[2*M_Q + m]   = sqrtf(b1);
        fin[3*M_Q + m]   = sqrtf(b2);
    }
}

// ---------------------------------------------------------------------------
// Final stats: counts, means, percentiles (numpy-linear) via bitonic sort.
// Single block, 1024 threads.
// ---------------------------------------------------------------------------
__device__ __forceinline__ void sort_and_pct(float* s, int t, float* dst) {
    __syncthreads();
    for (int k = 2; k <= 1024; k <<= 1) {
        for (int j = k >> 1; j > 0; j >>= 1) {
            __syncthreads();
            int ixj = t ^ j;
            if (ixj > t) {
                float a = s[t], b = s[ixj];
                bool up = ((t & k) == 0);
                if ((a > b) == up) { s[t] = b; s[ixj] = a; }
            }
        }
    }
    __syncthreads();
    if (t < 5) {
        const float P[5] = {10.f, 25.f, 50.f, 75.f, 90.f};
        float q = P[t] * 1023.0f / 100.0f;
        int lo = (int)q;
        float fr = q - (float)lo;
        dst[t] = s[lo] + fr * (s[lo + 1] - s[lo]);
    }
    __syncthreads();
}

__global__ __launch_bounds__(1024) void stats_kernel(
    const float* __restrict__ fin, float* __restrict__ out)
{
    __shared__ float s[1024];
    __shared__ float red[16][6];
    const int t = threadIdx.x;

    float m1 = fin[t];
    float m2 = fin[1024 + t];
    float s1 = fin[2048 + t];
    float s2 = fin[3072 + t];

    const float T = 1.0f / 3.0f;
    float v[6];
    v[0] = (m1 < T * s1 && m1 < T * m2) ? 1.0f : 0.0f;
    v[1] = (s1 < T * m1 && s1 < T * s2) ? 1.0f : 0.0f;
    v[2] = m1; v[3] = s1; v[4] = m2; v[5] = s2;

    #pragma unroll
    for (int off = 32; off > 0; off >>= 1)
        #pragma unroll
        for (int i = 0; i < 6; ++i) v[i] += __shfl_xor(v[i], off);

    int lane = t & 63, wid = t >> 6;
    if (lane == 0) {
        #pragma unroll
        for (int i = 0; i < 6; ++i) red[wid][i] = v[i];
    }
    __syncthreads();
    if (t == 0) {
        float a[6] = {0, 0, 0, 0, 0, 0};
        for (int w = 0; w < 16; ++w)
            for (int i = 0; i < 6; ++i) a[i] += red[w][i];
        out[0] = a[0];
        out[1] = a[1];
        out[2] = a[2] / 1024.0f;
        out[3] = a[3] / 1024.0f;
        out[4] = a[4] / 1024.0f;
        out[5] = a[5] / 1024.0f;
    }

    s[t] = m1;
    sort_and_pct(s, t, out + 6);
    s[t] = s1;
    sort_and_pct(s, t, out + 11);
}

// ---------------------------------------------------------------------------
extern "C" void kernel_launch(void* const* d_in, const int* in_sizes, int n_in,
                              void* d_out, int out_size, void* d_ws, size_t ws_size,
                              hipStream_t stream) {
    const float* Q  = (const float*)d_in[0];   // learned_means [1024,512]
    const float* TM = (const float*)d_in[1];   // true_means   [4096,512]
    const float* XT = (const float*)d_in[2];   // X_train      [16384,512]
    float* out = (float*)d_out;

    float* ws = (float*)d_ws;
    float* qn = ws;                                         // 1024
    float* dn = ws + M_Q;                                   // 20480 (TM then XT)
    float* partial = dn + (P_TM + P_XT);                    // 1024*320*2 = 655360
    float* fin = partial + (size_t)M_Q * NCHUNK_TOT * 2;    // 4096

    norms_kernel<<<dim3(M_Q / 4),  256, 0, stream>>>(Q,  qn, M_Q);
    norms_kernel<<<dim3(P_TM / 4), 256, 0, stream>>>(TM, dn, P_TM);
    norms_kernel<<<dim3(P_XT / 4), 256, 0, stream>>>(XT, dn + P_TM, P_XT);

    dist_top2_kernel<<<dim3(NCHUNK_TM, M_Q / BM), 256, 0, stream>>>(
        Q, TM, qn, dn, partial, 0);
    dist_top2_kernel<<<dim3(NCHUNK_XT, M_Q / BM), 256, 0, stream>>>(
        Q, XT, qn, dn + P_TM, partial, NCHUNK_TM);

    reduce_top2_kernel<<<dim3(M_Q / 4), 256, 0, stream>>>(partial, fin);
    stats_kernel<<<dim3(1), 1024, 0, stream>>>(fin, out);
}

// Round 3
// 108.370 us; speedup vs baseline: 3.0091x; 1.2826x over previous
//
#include <hip/hip_runtime.h>
#include <hip/hip_bf16.h>

// ---------------------------------------------------------------------------
// LearnedMeans: 2-NN distances (queries=learned_means vs {true_means, X_train})
// + statistics. R3 structure:
//   1) convert_norms_kernel: f32 -> bf16 copy of all matrices + row sq-norms
//   2) dist_mfma_kernel: fused 128x128xBK64 MFMA GEMM over concatenated
//      dataset (20480 pts), global_load_lds(16B) staging with st_16x32-style
//      XOR swizzle (inverse-swizzled per-lane SOURCE, linear LDS dest,
//      swizzled ds_read). Per-wave 64x64 output, per-64-col-chunk top-2.
//   3) reduce_top2_kernel: wave-per-query chunk merge (unchanged from R2)
//   4) stats_kernel: counts/means/percentiles (unchanged)
// Fallback to the verified R2 path if ws_size < ~23.7 MB.
// ---------------------------------------------------------------------------

#define DIM 512
#define M_Q 1024
#define P_TM 4096
#define P_XT 16384
#define P_ALL (P_TM + P_XT)          // 20480
#define NROWS_ALL (M_Q + P_ALL)      // 21504

#define BM 128
#define BN 128
#define BK 64
#define CHUNK 64
#define NCHUNK_TM (P_TM / CHUNK)     // 64
#define NCHUNK_TOT (P_ALL / CHUNK)   // 320
#define BIGF 3.402823466e38f

typedef __bf16 bf16x8 __attribute__((ext_vector_type(8)));
typedef float f32x4 __attribute__((ext_vector_type(4)));
typedef unsigned short u16x8 __attribute__((ext_vector_type(8)));

__device__ __forceinline__ unsigned short f2bf(float f) {
    unsigned int u = __float_as_uint(f);
    unsigned int r = (u + 0x7fffu + ((u >> 16) & 1u)) >> 16;
    return (unsigned short)r;
}

__device__ __forceinline__ void merge1(float v, float& d1, float& d2) {
    if (v < d1) { d2 = d1; d1 = v; }
    else if (v < d2) { d2 = v; }
}

__device__ __forceinline__ void top2_shfl16(float& d1, float& d2) {
    #pragma unroll
    for (int off = 1; off < 16; off <<= 1) {
        float o1 = __shfl_xor(d1, off);
        float o2 = __shfl_xor(d2, off);
        float n1 = fminf(d1, o1);
        float n2 = fminf(fmaxf(d1, o1), fminf(d2, o2));
        d1 = n1; d2 = n2;
    }
}

__device__ __forceinline__ void async_copy16(const void* g, void* l) {
    __builtin_amdgcn_global_load_lds(
        (const __attribute__((address_space(1))) void*)g,
        (__attribute__((address_space(3))) void*)l,
        16, 0, 0);
}

// ---------------------------------------------------------------------------
// Pass 1: f32 -> bf16 + squared norms. One wave per row (512 elems, 8/lane).
// Rows [0,1024): Q -> Qb/qn. Rows [1024,21504): TM then XT -> Db/dn.
// ---------------------------------------------------------------------------
__global__ __launch_bounds__(256) void convert_norms_kernel(
    const float* __restrict__ Q, const float* __restrict__ TMat,
    const float* __restrict__ XT,
    unsigned short* __restrict__ Qb, unsigned short* __restrict__ Db,
    float* __restrict__ qn, float* __restrict__ dn)
{
    const int wid = threadIdx.x >> 6;
    const int lane = threadIdx.x & 63;
    const int row = blockIdx.x * 4 + wid;

    const float* src;
    unsigned short* dst;
    float* ndst;
    if (row < M_Q) {
        src = Q + (size_t)row * DIM; dst = Qb + (size_t)row * DIM; ndst = qn + row;
    } else {
        int r = row - M_Q;
        src = (row < M_Q + P_TM) ? (TMat + (size_t)r * DIM)
                                 : (XT + (size_t)(row - (M_Q + P_TM)) * DIM);
        dst = Db + (size_t)r * DIM; ndst = dn + r;
    }

    const float* p = src + lane * 8;
    float4 v0 = *(const float4*)p;
    float4 v1 = *(const float4*)(p + 4);
    float s = v0.x*v0.x + v0.y*v0.y + v0.z*v0.z + v0.w*v0.w
            + v1.x*v1.x + v1.y*v1.y + v1.z*v1.z + v1.w*v1.w;

    u16x8 o;
    o[0]=f2bf(v0.x); o[1]=f2bf(v0.y); o[2]=f2bf(v0.z); o[3]=f2bf(v0.w);
    o[4]=f2bf(v1.x); o[5]=f2bf(v1.y); o[6]=f2bf(v1.z); o[7]=f2bf(v1.w);
    *(u16x8*)(dst + lane * 8) = o;

    #pragma unroll
    for (int off = 32; off > 0; off >>= 1) s += __shfl_xor(s, off);
    if (lane == 0) *ndst = s;
}

// ---------------------------------------------------------------------------
// Pass 2: MFMA distance + per-64-col-chunk top-2.
// Block: 128 queries x 128 dataset rows. 4 waves in 2x2; wave (wr,wc) owns a
// 64x64 sub-tile = acc[4][4] of 16x16 frags, K swept in BK=64 (2 MFMA k-halves).
// LDS tiles [128][64] bf16 (16 KB each), XOR-swizzled: logical chunk c of row r
// (16B units within the 128B row) is stored at chunk c^(r&7). Staging writes
// linearly (global_load_lds, dest = wave-uniform base + lane*16) with the
// INVERSE swizzle folded into each lane's global source address; ds_read
// applies the same XOR -> 2 lanes/bank (free, m136).
// ---------------------------------------------------------------------------
__global__ __launch_bounds__(256) void dist_mfma_kernel(
    const unsigned short* __restrict__ Qb,   // [M_Q][DIM] bf16
    const unsigned short* __restrict__ Db,   // [P_ALL][DIM] bf16
    const float* __restrict__ qn,            // [M_Q]
    const float* __restrict__ dn,            // [P_ALL]
    float* __restrict__ partial)             // [M_Q][NCHUNK_TOT][2]
{
    __shared__ __align__(16) unsigned short As[BM * BK];
    __shared__ __align__(16) unsigned short Bs[BN * BK];

    const int tid  = threadIdx.x;
    const int lane = tid & 63;
    const int wid  = tid >> 6;          // 0..3
    const int wr   = wid >> 1;          // 0..1 (row half)
    const int wc   = wid & 1;           // 0..1 (col half)
    const int mBase = blockIdx.y * BM;
    const int nBase = blockIdx.x * BN;

    // --- staging precompute: 4 slabs of 1KB per wave for each of A,B ---
    const unsigned short* srcA[4];
    const unsigned short* srcB[4];
    int ldsOff[4];                       // ushort offset of slab base (uniform)
    #pragma unroll
    for (int s = 0; s < 4; ++s) {
        int phys = (s * 4 + wid) * 1024 + lane * 16;   // byte offset in tile
        int row  = phys >> 7;                          // /128B per row
        int cphys = (phys >> 4) & 7;                   // 16B chunk in row
        int clog  = cphys ^ (row & 7);                 // inverse swizzle
        srcA[s] = Qb + (size_t)(mBase + row) * DIM + clog * 8;
        srcB[s] = Db + (size_t)(nBase + row) * DIM + clog * 8;
        ldsOff[s] = (s * 4 + wid) * 512;               // 1024B = 512 ushort
    }

    // --- ds_read fragment addresses (byte offsets), [k-half][mi] ---
    int addrA[2][4], addrB[2][4];
    const int kb = (lane >> 4) * 16;     // k-frag byte offset within row
    #pragma unroll
    for (int mi = 0; mi < 4; ++mi) {
        int rowA = wr * 64 + mi * 16 + (lane & 15);
        int a0 = rowA * 128 + (kb ^ ((rowA & 7) << 4));
        addrA[0][mi] = a0; addrA[1][mi] = a0 ^ 64;
        int rowB = wc * 64 + mi * 16 + (lane & 15);
        int b0 = rowB * 128 + (kb ^ ((rowB & 7) << 4));
        addrB[0][mi] = b0; addrB[1][mi] = b0 ^ 64;
    }

    f32x4 acc[4][4];
    #pragma unroll
    for (int mi = 0; mi < 4; ++mi)
        #pragma unroll
        for (int ni = 0; ni < 4; ++ni)
            #pragma unroll
            for (int i = 0; i < 4; ++i) acc[mi][ni][i] = 0.0f;

    const char* asb = (const char*)As;
    const char* bsb = (const char*)Bs;

    for (int ks = 0; ks < DIM; ks += BK) {
        #pragma unroll
        for (int s = 0; s < 4; ++s) {
            async_copy16(srcA[s] + ks, &As[ldsOff[s]]);
            async_copy16(srcB[s] + ks, &Bs[ldsOff[s]]);
        }
        __syncthreads();   // compiler drains vmcnt before barrier

        bf16x8 aF[2][4], bF[2][4];
        #pragma unroll
        for (int h = 0; h < 2; ++h)
            #pragma unroll
            for (int mi = 0; mi < 4; ++mi) {
                aF[h][mi] = *(const bf16x8*)(asb + addrA[h][mi]);
                bF[h][mi] = *(const bf16x8*)(bsb + addrB[h][mi]);
            }
        #pragma unroll
        for (int mi = 0; mi < 4; ++mi)
            #pragma unroll
            for (int ni = 0; ni < 4; ++ni) {
                acc[mi][ni] = __builtin_amdgcn_mfma_f32_16x16x32_bf16(
                    aF[0][mi], bF[0][ni], acc[mi][ni], 0, 0, 0);
                acc[mi][ni] = __builtin_amdgcn_mfma_f32_16x16x32_bf16(
                    aF[1][mi], bF[1][ni], acc[mi][ni], 0, 0, 0);
            }
        __syncthreads();   // protect LDS before next stage overwrites
    }

    // --- epilogue: sq = q2 + d2 - 2*dot; top-2 per (row, 64-col chunk) ---
    const int g = lane >> 4;             // row sub-group
    const int c = lane & 15;             // col within 16

    float q2[4][4];
    #pragma unroll
    for (int mi = 0; mi < 4; ++mi)
        #pragma unroll
        for (int r = 0; r < 4; ++r)
            q2[mi][r] = qn[mBase + wr * 64 + mi * 16 + g * 4 + r];

    float d1[4][4], d2[4][4];
    #pragma unroll
    for (int mi = 0; mi < 4; ++mi)
        #pragma unroll
        for (int r = 0; r < 4; ++r) { d1[mi][r] = BIGF; d2[mi][r] = BIGF; }

    #pragma unroll
    for (int ni = 0; ni < 4; ++ni) {
        float dd = dn[nBase + wc * 64 + ni * 16 + c];
        #pragma unroll
        for (int mi = 0; mi < 4; ++mi)
            #pragma unroll
            for (int r = 0; r < 4; ++r) {
                float sq = q2[mi][r] + dd - 2.0f * acc[mi][ni][r];
                sq = fmaxf(sq, 0.0f);
                merge1(sq, d1[mi][r], d2[mi][r]);
            }
    }

    #pragma unroll
    for (int mi = 0; mi < 4; ++mi)
        #pragma unroll
        for (int r = 0; r < 4; ++r)
            top2_shfl16(d1[mi][r], d2[mi][r]);

    if (c == 0) {
        int chunkG = blockIdx.x * 2 + wc;
        #pragma unroll
        for (int mi = 0; mi < 4; ++mi)
            #pragma unroll
            for (int r = 0; r < 4; ++r) {
                int row = mBase + wr * 64 + mi * 16 + g * 4 + r;
                size_t base = ((size_t)row * NCHUNK_TOT + chunkG) * 2;
                partial[base]     = d1[mi][r];
                partial[base + 1] = d2[mi][r];
            }
    }
}

// ---------------------------------------------------------------------------
// Pass 3: merge per-chunk top-2 partials (one wave per query, unchanged R2).
// fin layout: dm1[0..1024), dm2[1024..2048), ds1[2048..3072), ds2[3072..4096)
// ---------------------------------------------------------------------------
__global__ __launch_bounds__(256) void reduce_top2_kernel(
    const float* __restrict__ partial, float* __restrict__ fin)
{
    const int wid  = threadIdx.x >> 6;
    const int lane = threadIdx.x & 63;
    const int m = blockIdx.x * 4 + wid;
    const float* p = partial + (size_t)m * (NCHUNK_TOT * 2);

    float2 v = *(const float2*)(p + 2 * lane);
    float a1 = fminf(v.x, v.y), a2 = fmaxf(v.x, v.y);
    #pragma unroll
    for (int off = 32; off > 0; off >>= 1) {
        float o1 = __shfl_xor(a1, off);
        float o2 = __shfl_xor(a2, off);
        float n1 = fminf(a1, o1);
        float n2 = fminf(fmaxf(a1, o1), fminf(a2, o2));
        a1 = n1; a2 = n2;
    }

    const float* px = p + 2 * NCHUNK_TM + lane * 8;
    float4 w0 = *(const float4*)px;
    float4 w1 = *(const float4*)(px + 4);
    float b1 = BIGF, b2 = BIGF;
    merge1(w0.x, b1, b2); merge1(w0.y, b1, b2);
    merge1(w0.z, b1, b2); merge1(w0.w, b1, b2);
    merge1(w1.x, b1, b2); merge1(w1.y, b1, b2);
    merge1(w1.z, b1, b2); merge1(w1.w, b1, b2);
    #pragma unroll
    for (int off = 32; off > 0; off >>= 1) {
        float o1 = __shfl_xor(b1, off);
        float o2 = __shfl_xor(b2, off);
        float n1 = fminf(b1, o1);
        float n2 = fminf(fmaxf(b1, o1), fminf(b2, o2));
        b1 = n1; b2 = n2;
    }

    if (lane == 0) {
        fin[m]           = sqrtf(a1);
        fin[M_Q + m]     = sqrtf(a2);
        fin[2*M_Q + m]   = sqrtf(b1);
        fin[3*M_Q + m]   = sqrtf(b2);
    }
}

// ---------------------------------------------------------------------------
// Pass 4: stats (unchanged).
// ---------------------------------------------------------------------------
__device__ __forceinline__ void sort_and_pct(float* s, int t, float* dst) {
    __syncthreads();
    for (int k = 2; k <= 1024; k <<= 1) {
        for (int j = k >> 1; j > 0; j >>= 1) {
            __syncthreads();
            int ixj = t ^ j;
            if (ixj > t) {
                float a = s[t], b = s[ixj];
                bool up = ((t & k) == 0);
                if ((a > b) == up) { s[t] = b; s[ixj] = a; }
            }
        }
    }
    __syncthreads();
    if (t < 5) {
        const float P[5] = {10.f, 25.f, 50.f, 75.f, 90.f};
        float q = P[t] * 1023.0f / 100.0f;
        int lo = (int)q;
        float fr = q - (float)lo;
        dst[t] = s[lo] + fr * (s[lo + 1] - s[lo]);
    }
    __syncthreads();
}

__global__ __launch_bounds__(1024) void stats_kernel(
    const float* __restrict__ fin, float* __restrict__ out)
{
    __shared__ float s[1024];
    __shared__ float red[16][6];
    const int t = threadIdx.x;

    float m1 = fin[t];
    float m2 = fin[1024 + t];
    float s1 = fin[2048 + t];
    float s2 = fin[3072 + t];

    const float T = 1.0f / 3.0f;
    float v[6];
    v[0] = (m1 < T * s1 && m1 < T * m2) ? 1.0f : 0.0f;
    v[1] = (s1 < T * m1 && s1 < T * s2) ? 1.0f : 0.0f;
    v[2] = m1; v[3] = s1; v[4] = m2; v[5] = s2;

    #pragma unroll
    for (int off = 32; off > 0; off >>= 1)
        #pragma unroll
        for (int i = 0; i < 6; ++i) v[i] += __shfl_xor(v[i], off);

    int lane = t & 63, wid = t >> 6;
    if (lane == 0) {
        #pragma unroll
        for (int i = 0; i < 6; ++i) red[wid][i] = v[i];
    }
    __syncthreads();
    if (t == 0) {
        float a[6] = {0, 0, 0, 0, 0, 0};
        for (int w = 0; w < 16; ++w)
            for (int i = 0; i < 6; ++i) a[i] += red[w][i];
        out[0] = a[0];
        out[1] = a[1];
        out[2] = a[2] / 1024.0f;
        out[3] = a[3] / 1024.0f;
        out[4] = a[4] / 1024.0f;
        out[5] = a[5] / 1024.0f;
    }

    s[t] = m1;
    sort_and_pct(s, t, out + 6);
    s[t] = s1;
    sort_and_pct(s, t, out + 11);
}

// ---------------------------------------------------------------------------
// Fallback path (verified R2 kernels) — used only if ws_size is too small
// for the bf16 copies (~23.7 MB needed).
// ---------------------------------------------------------------------------
__global__ __launch_bounds__(256) void norms_kernel_fb(
    const float* __restrict__ src, float* __restrict__ dst, int nrows)
{
    int wid = threadIdx.x >> 6;
    int lane = threadIdx.x & 63;
    int row = blockIdx.x * 4 + wid;
    if (row >= nrows) return;
    const float* p = src + (size_t)row * DIM + lane * 8;
    float4 v0 = *(const float4*)p;
    float4 v1 = *(const float4*)(p + 4);
    float s = v0.x*v0.x + v0.y*v0.y + v0.z*v0.z + v0.w*v0.w
            + v1.x*v1.x + v1.y*v1.y + v1.z*v1.z + v1.w*v1.w;
    #pragma unroll
    for (int off = 32; off > 0; off >>= 1) s += __shfl_xor(s, off);
    if (lane == 0) dst[row] = s;
}

__global__ __launch_bounds__(256) void dist_top2_kernel_fb(
    const float* __restrict__ Q, const float* __restrict__ Dset,
    const float* __restrict__ qn, const float* __restrict__ dn,
    float* __restrict__ partial, int chunkGlobalOffset)
{
    __shared__ __align__(16) unsigned short As[64][40];
    __shared__ __align__(16) unsigned short Bs[64][40];

    const int tid  = threadIdx.x;
    const int lane = tid & 63;
    const int wid  = tid >> 6;
    const int mBase = blockIdx.y * 64;
    const int nBase = blockIdx.x * 64;

    const int srow = tid >> 2;
    const int skc  = (tid & 3) * 8;

    const float* qrow = Q    + (size_t)(mBase + srow) * DIM + skc;
    const float* drow = Dset + (size_t)(nBase + srow) * DIM + skc;

    f32x4 acc[4];
    #pragma unroll
    for (int nt = 0; nt < 4; ++nt)
        #pragma unroll
        for (int i = 0; i < 4; ++i) acc[nt][i] = 0.0f;

    const int frow = lane & 15;
    const int fk   = (lane >> 4) * 8;

    for (int ks = 0; ks < DIM; ks += 32) {
        float4 a0 = *(const float4*)(qrow + ks);
        float4 a1 = *(const float4*)(qrow + ks + 4);
        float4 b0 = *(const float4*)(drow + ks);
        float4 b1 = *(const float4*)(drow + ks + 4);

        u16x8 va, vb;
        va[0]=f2bf(a0.x); va[1]=f2bf(a0.y); va[2]=f2bf(a0.z); va[3]=f2bf(a0.w);
        va[4]=f2bf(a1.x); va[5]=f2bf(a1.y); va[6]=f2bf(a1.z); va[7]=f2bf(a1.w);
        vb[0]=f2bf(b0.x); vb[1]=f2bf(b0.y); vb[2]=f2bf(b0.z); vb[3]=f2bf(b0.w);
        vb[4]=f2bf(b1.x); vb[5]=f2bf(b1.y); vb[6]=f2bf(b1.z); vb[7]=f2bf(b1.w);

        *(u16x8*)(&As[srow][skc]) = va;
        *(u16x8*)(&Bs[srow][skc]) = vb;
        __syncthreads();

        bf16x8 af = *(const bf16x8*)(&As[wid * 16 + frow][fk]);
        #pragma unroll
        for (int nt = 0; nt < 4; ++nt) {
            bf16x8 bf = *(const bf16x8*)(&Bs[nt * 16 + frow][fk]);
            acc[nt] = __builtin_amdgcn_mfma_f32_16x16x32_bf16(af, bf, acc[nt], 0, 0, 0);
        }
        __syncthreads();
    }

    const int rbase = mBase + wid * 16 + ((lane >> 4) << 2);
    float q2[4];
    #pragma unroll
    for (int r = 0; r < 4; ++r) q2[r] = qn[rbase + r];

    float d1[4], d2[4];
    #pragma unroll
    for (int r = 0; r < 4; ++r) { d1[r] = BIGF; d2[r] = BIGF; }

    #pragma unroll
    for (int nt = 0; nt < 4; ++nt) {
        float dd = dn[nBase + nt * 16 + (lane & 15)];
        #pragma unroll
        for (int r = 0; r < 4; ++r) {
            float sq = q2[r] + dd - 2.0f * acc[nt][r];
            sq = fmaxf(sq, 0.0f);
            merge1(sq, d1[r], d2[r]);
        }
    }

    #pragma unroll
    for (int r = 0; r < 4; ++r) top2_shfl16(d1[r], d2[r]);

    if ((lane & 15) == 0) {
        int chunkG = chunkGlobalOffset + blockIdx.x;
        #pragma unroll
        for (int r = 0; r < 4; ++r) {
            size_t base = ((size_t)(rbase + r) * NCHUNK_TOT + chunkG) * 2;
            partial[base]     = d1[r];
            partial[base + 1] = d2[r];
        }
    }
}

// ---------------------------------------------------------------------------
extern "C" void kernel_launch(void* const* d_in, const int* in_sizes, int n_in,
                              void* d_out, int out_size, void* d_ws, size_t ws_size,
                              hipStream_t stream) {
    const float* Q  = (const float*)d_in[0];
    const float* TM = (const float*)d_in[1];
    const float* XT = (const float*)d_in[2];
    float* out = (float*)d_out;

    const size_t needMain =
        (size_t)M_Q * DIM * 2 + (size_t)P_ALL * DIM * 2 +
        4 * ((size_t)M_Q + P_ALL + (size_t)M_Q * NCHUNK_TOT * 2 + 4 * M_Q);

    if (ws_size >= needMain) {
        char* w = (char*)d_ws;
        unsigned short* Qb = (unsigned short*)w;                   // 1 MB
        unsigned short* Db = (unsigned short*)(w + (size_t)M_Q * DIM * 2);
        float* qn = (float*)(w + (size_t)M_Q * DIM * 2 + (size_t)P_ALL * DIM * 2);
        float* dn = qn + M_Q;
        float* partial = dn + P_ALL;
        float* fin = partial + (size_t)M_Q * NCHUNK_TOT * 2;

        convert_norms_kernel<<<dim3(NROWS_ALL / 4), 256, 0, stream>>>(
            Q, TM, XT, Qb, Db, qn, dn);
        dist_mfma_kernel<<<dim3(P_ALL / BN, M_Q / BM), 256, 0, stream>>>(
            Qb, Db, qn, dn, partial);
        reduce_top2_kernel<<<dim3(M_Q / 4), 256, 0, stream>>>(partial, fin);
        stats_kernel<<<dim3(1), 1024, 0, stream>>>(fin, out);
    } else {
        float* ws = (float*)d_ws;
        float* qn = ws;
        float* dn = ws + M_Q;
        float* partial = dn + P_ALL;
        float* fin = partial + (size_t)M_Q * NCHUNK_TOT * 2;

        norms_kernel_fb<<<dim3(M_Q / 4),  256, 0, stream>>>(Q,  qn, M_Q);
        norms_kernel_fb<<<dim3(P_TM / 4), 256, 0, stream>>>(TM, dn, P_TM);
        norms_kernel_fb<<<dim3(P_XT / 4), 256, 0, stream>>>(XT, dn + P_TM, P_XT);
        dist_top2_kernel_fb<<<dim3(P_TM / 64, M_Q / 64), 256, 0, stream>>>(
            Q, TM, qn, dn, partial, 0);
        dist_top2_kernel_fb<<<dim3(P_XT / 64, M_Q / 64), 256, 0, stream>>>(
            Q, XT, qn, dn + P_TM, partial, NCHUNK_TM);
        reduce_top2_kernel<<<dim3(M_Q / 4), 256, 0, stream>>>(partial, fin);
        stats_kernel<<<dim3(1), 1024, 0, stream>>>(fin, out);
    }
}